// Round 1
// baseline (57.676 us; speedup 1.0000x reference)
//
#include <hip/hip_runtime.h>

namespace {
constexpr int kB = 32, kT = 30, kD = 512, kL = 196;
constexpr int kLC = 7, kNCHUNK = kL / kLC;   // 28 l-chunks
constexpr int kTG = 5, kNTG = kT / kTG;      // 6 t-groups
constexpr float kK = 2.8853900817779268f;    // 2*log2(e)

__device__ __forceinline__ float sig_r(float a) {
  // r = 1/(exp2(a)+1) with a = 2*log2e*z  =>  tanh(z) = 1 - 2r
  return __builtin_amdgcn_rcpf(__builtin_amdgcn_exp2f(a) + 1.0f);
}

// sC[b,t,d] = (x + wordemb) * 2log2e
__global__ __launch_bounds__(256) void k_precompute_s(
    const float* __restrict__ x, const float* __restrict__ w,
    float* __restrict__ sC) {
  const float4* x4 = reinterpret_cast<const float4*>(x);
  const float4* w4 = reinterpret_cast<const float4*>(w);
  float4* s4 = reinterpret_cast<float4*>(sC);
  const int n4 = kB * kT * kD / 4;
  for (int i = blockIdx.x * blockDim.x + threadIdx.x; i < n4;
       i += gridDim.x * blockDim.x) {
    float4 a = x4[i], b = w4[i];
    float4 r;
    r.x = (a.x + b.x) * kK;
    r.y = (a.y + b.y) * kK;
    r.z = (a.z + b.z) * kK;
    r.w = (a.w + b.w) * kK;
    s4[i] = r;
  }
}

// g[b,t,l] = sum_d vw[d] * r(sC[b,t,d] + yC[b,l,d]);  e = const - 2g (const cancels in softmax)
__global__ __launch_bounds__(256) void k_score(
    const float* __restrict__ img, const float* __restrict__ sC,
    const float* __restrict__ vw, float* __restrict__ g_out) {
  __shared__ __align__(16) float yC[kLC * kD];
  const int b = blockIdx.y;
  const int l0 = blockIdx.x * kLC;
  const int tid = threadIdx.x;
  // stage scaled img rows l0..l0+6 into LDS (read once per block)
  const float4* ib4 =
      reinterpret_cast<const float4*>(img + (size_t)(b * kL + l0) * kD);
  float4* y4 = reinterpret_cast<float4*>(yC);
  for (int i = tid; i < kLC * kD / 4; i += 256) {
    float4 v = ib4[i];
    v.x *= kK; v.y *= kK; v.z *= kK; v.w *= kK;
    y4[i] = v;
  }
  const int lane = tid & 63;
  const int wid = tid >> 6;
  // each lane owns d in {4*lane..4*lane+3} U {256+4*lane..256+4*lane+3}
  const float4 vw0 = *reinterpret_cast<const float4*>(vw + 4 * lane);
  const float4 vw1 = *reinterpret_cast<const float4*>(vw + 256 + 4 * lane);
  __syncthreads();
  // wave -> t range: {8,8,7,7}
  const int tstart = (wid < 2) ? wid * 8 : 16 + (wid - 2) * 7;
  const int tcount = (wid < 2) ? 8 : 7;
  for (int tt = 0; tt < tcount; ++tt) {
    const int t = tstart + tt;
    const float* sb = sC + (size_t)(b * kT + t) * kD;
    const float4 s0 = *reinterpret_cast<const float4*>(sb + 4 * lane);
    const float4 s1 = *reinterpret_cast<const float4*>(sb + 256 + 4 * lane);
    for (int l = 0; l < kLC; ++l) {
      const float* yb = yC + l * kD;
      const float4 y0 = *reinterpret_cast<const float4*>(yb + 4 * lane);
      const float4 y1 = *reinterpret_cast<const float4*>(yb + 256 + 4 * lane);
      float acc = 0.f;
      acc = fmaf(vw0.x, sig_r(s0.x + y0.x), acc);
      acc = fmaf(vw0.y, sig_r(s0.y + y0.y), acc);
      acc = fmaf(vw0.z, sig_r(s0.z + y0.z), acc);
      acc = fmaf(vw0.w, sig_r(s0.w + y0.w), acc);
      acc = fmaf(vw1.x, sig_r(s1.x + y1.x), acc);
      acc = fmaf(vw1.y, sig_r(s1.y + y1.y), acc);
      acc = fmaf(vw1.z, sig_r(s1.z + y1.z), acc);
      acc = fmaf(vw1.w, sig_r(s1.w + y1.w), acc);
#pragma unroll
      for (int m = 1; m < 64; m <<= 1) acc += __shfl_xor(acc, m, 64);
      if (lane == 0) g_out[(size_t)(b * kT + t) * kL + l0 + l] = acc;
    }
  }
}

// softmax over l of (-2g) (up to cancelled constant), then context = img^T alpha
__global__ __launch_bounds__(256) void k_softmax_ctx(
    const float* __restrict__ img, const float* __restrict__ g_in,
    float* __restrict__ out) {
  __shared__ __align__(16) float alpha[kL][8];  // [l][t'] padded to 8
  const int b = blockIdx.y;
  const int t0 = blockIdx.x * kTG;
  const int tid = threadIdx.x;
  const int lane = tid & 63;
  const int wid = tid >> 6;
  for (int tp = wid; tp < kTG; tp += 4) {
    const float* gb = g_in + (size_t)(b * kT + t0 + tp) * kL;
    // u = g * 2log2e; e*log2e = const - u; alpha ~ exp2(min(u) - u)
    float u0 = gb[lane] * kK;
    float u1 = gb[lane + 64] * kK;
    float u2 = gb[lane + 128] * kK;
    float u3 = (lane < kL - 192) ? gb[lane + 192] * kK : __builtin_inff();
    float m = fminf(fminf(u0, u1), fminf(u2, u3));
#pragma unroll
    for (int mm = 1; mm < 64; mm <<= 1) m = fminf(m, __shfl_xor(m, mm, 64));
    float e0 = __builtin_amdgcn_exp2f(m - u0);
    float e1 = __builtin_amdgcn_exp2f(m - u1);
    float e2 = __builtin_amdgcn_exp2f(m - u2);
    float e3 = (lane < kL - 192) ? __builtin_amdgcn_exp2f(m - u3) : 0.f;
    float s = e0 + e1 + e2 + e3;
#pragma unroll
    for (int mm = 1; mm < 64; mm <<= 1) s += __shfl_xor(s, mm, 64);
    float rs = __builtin_amdgcn_rcpf(s);
    alpha[lane][tp] = e0 * rs;
    alpha[lane + 64][tp] = e1 * rs;
    alpha[lane + 128][tp] = e2 * rs;
    if (lane < kL - 192) alpha[lane + 192][tp] = e3 * rs;
  }
  __syncthreads();
  float acc[kTG][2];
#pragma unroll
  for (int tp = 0; tp < kTG; ++tp) { acc[tp][0] = 0.f; acc[tp][1] = 0.f; }
  // thread owns d in {2*tid, 2*tid+1}; 5 t-accumulators per img load
  const float* ib = img + (size_t)b * kL * kD + 2 * tid;
  for (int l = 0; l < kL; ++l) {
    const float2 v = *reinterpret_cast<const float2*>(ib + (size_t)l * kD);
    const float4 a03 = *reinterpret_cast<const float4*>(&alpha[l][0]);
    const float a4 = alpha[l][4];
    acc[0][0] = fmaf(v.x, a03.x, acc[0][0]);
    acc[0][1] = fmaf(v.y, a03.x, acc[0][1]);
    acc[1][0] = fmaf(v.x, a03.y, acc[1][0]);
    acc[1][1] = fmaf(v.y, a03.y, acc[1][1]);
    acc[2][0] = fmaf(v.x, a03.z, acc[2][0]);
    acc[2][1] = fmaf(v.y, a03.z, acc[2][1]);
    acc[3][0] = fmaf(v.x, a03.w, acc[3][0]);
    acc[3][1] = fmaf(v.y, a03.w, acc[3][1]);
    acc[4][0] = fmaf(v.x, a4, acc[4][0]);
    acc[4][1] = fmaf(v.y, a4, acc[4][1]);
  }
#pragma unroll
  for (int tp = 0; tp < kTG; ++tp) {
    float2 o;
    o.x = acc[tp][0];
    o.y = acc[tp][1];
    *reinterpret_cast<float2*>(out + (size_t)(b * kT + t0 + tp) * kD + 2 * tid) = o;
  }
}
}  // namespace

extern "C" void kernel_launch(void* const* d_in, const int* in_sizes, int n_in,
                              void* d_out, int out_size, void* d_ws, size_t ws_size,
                              hipStream_t stream) {
  const float* x = (const float*)d_in[0];
  const float* wordemb = (const float*)d_in[1];
  const float* img = (const float*)d_in[2];
  const float* vw = (const float*)d_in[3];
  // v_b (d_in[4]) cancels in the softmax along with sum(v_w) — unused by design.
  float* out = (float*)d_out;
  float* sC = (float*)d_ws;                   // kB*kT*kD floats (1.97 MB)
  float* g = sC + (size_t)kB * kT * kD;       // kB*kT*kL floats (751 KB)
  hipLaunchKernelGGL(k_precompute_s, dim3(480), dim3(256), 0, stream, x, wordemb, sC);
  hipLaunchKernelGGL(k_score, dim3(kNCHUNK, kB), dim3(256), 0, stream, img, sC, vw, g);
  hipLaunchKernelGGL(k_softmax_ctx, dim3(kNTG, kB), dim3(256), 0, stream, img, g, out);
}